// Round 8
// baseline (45.513 us; speedup 1.0000x reference)
//
#include <hip/hip_runtime.h>

#define C2   2.8853900817779268f    //  2*log2(e)
#define NC2 -2.8853900817779268f    // -2*log2(e)

// Kernel 1: projection + exp precompute.
// Eq[b*512+q][h] = exp2(clamp(C2 * (queries @ Wq)[q][h], +-60)), Ek likewise (row-major).
__global__ __launch_bounds__(256) void proj_exp_kernel(
    const float* __restrict__ queries,
    const float* __restrict__ keys,
    const float* __restrict__ Wq,
    const float* __restrict__ Wk,
    float* __restrict__ Eq,
    float* __restrict__ Ek)
{
    __shared__ float w_lds[64 * 64];
    __shared__ float in_lds[256];

    const int t   = threadIdx.x;
    const int blk = blockIdx.x;          // 0..2047
    const int r0  = blk * 4;             // virtual row among 8192
    const bool isQ = (r0 < 4096);
    const float* __restrict__ W  = isQ ? Wq : Wk;
    const float* __restrict__ in = isQ ? queries : keys;
    float* __restrict__ Eo       = isQ ? Eq : Ek;
    const int rbase = isQ ? r0 : (r0 - 4096);

#pragma unroll
    for (int i = 0; i < 16; ++i)
        w_lds[t + i * 256] = W[t + i * 256];
    in_lds[t] = in[(size_t)rbase * 64 + t];
    __syncthreads();

    const int h  = t & 63;
    const int rl = t >> 6;               // 0..3 local row
    float acc = 0.f;
#pragma unroll
    for (int i = 0; i < 64; ++i)
        acc = fmaf(in_lds[rl * 64 + i], w_lds[i * 64 + h], acc);

    float x = fminf(fmaxf(acc * C2, -60.f), 60.f);  // bounded: products < 2^120
    Eo[(size_t)rbase * 64 + t] = __builtin_amdgcn_exp2f(x);
}

// Kernel 2: fused scores + softmax + PV, register-resident Ek, LDS-broadcast Eq/wv.
// Block = 8 waves x 64 lanes; lane l of wave w owns k = w*64+l (Ek row in 64 VGPRs)
// for 8 q-rows. Inner loop: ek in VGPRs, eq/wv via uniform-address ds_read_b128
// broadcasts (conflict-free, no SGPR pressure, no VMEM).
// __launch_bounds__(512, 2): 128-VGPR budget. Grid is 512 blocks = 2 blocks/CU
// = 16 waves/CU either way, and 128 VGPR supports exactly 16 waves/CU -> the
// relaxed bound costs zero occupancy but eliminates the R6 spill (ek needs
// ~100 live VGPRs; at 64 the allocator spilled ek to scratch: FETCH 76 MB).
// score'[q][k] = -2 * sum_h wv[h] * rcp(1 + Eq[q][h]*Ek[k][h])   (softmax-invariant shift)
// p = exp2(score'*log2e) without max subtraction (|score'| <= 2*sum|wv| ~ 26, fp32-safe;
// masked k -> p = 0 exactly). Score and PV phases are wave-local.
__global__ __launch_bounds__(512, 2) void attn_kernel(
    const float* __restrict__ Eq,
    const float* __restrict__ Ek,
    const float* __restrict__ wv,
    const float* __restrict__ V,
    const int* __restrict__ valid_lens,
    float* __restrict__ out)
{
    __shared__ float p_lds[8][512];        // [q][k]
    __shared__ float part_lds[8 * 8 * 64]; // [w][q][d] PV partials
    __shared__ float wsum[8][8];           // [w][q] per-wave softmax partial sums
    __shared__ float eq_lds[8 * 64];       // the block's 8 Eq rows
    __shared__ float wv_lds[64];

    const int t   = threadIdx.x;
    const int bid = blockIdx.x;          // 0..511
    const int b   = bid >> 6;
    const int q0  = (bid & 63) << 3;
    const int l   = t & 63;
    const int w   = __builtin_amdgcn_readfirstlane(threadIdx.x >> 6);  // uniform wave id
    const int vl  = valid_lens[b];
    const int k   = w * 64 + l;
    const bool kvalid = (k < vl);

    // stage Eq rows + wv into LDS (coalesced, one-time)
    eq_lds[t] = Eq[(size_t)(b * 512 + q0) * 64 + t];
    if (t < 64) wv_lds[t] = wv[t];

    // ---- lane-resident Ek row: 64 VGPRs, loaded once (L2-resident)
    float ek[64];
    {
        const float4* ekr = reinterpret_cast<const float4*>(Ek + (size_t)(b * 512 + k) * 64);
#pragma unroll
        for (int i = 0; i < 16; ++i) {
            float4 v = ekr[i];
            ek[4 * i + 0] = v.x; ek[4 * i + 1] = v.y;
            ek[4 * i + 2] = v.z; ek[4 * i + 3] = v.w;
        }
    }
    __syncthreads();                     // eq_lds/wv_lds ready

    // ---- score + softmax numerators: pure VALU/trans + uniform LDS broadcasts
#pragma unroll 1
    for (int q = 0; q < 8; ++q) {
        const float* eql = &eq_lds[q * 64];
        float a0 = 0.f, a1 = 0.f, a2 = 0.f, a3 = 0.f;
#pragma unroll
        for (int h = 0; h < 64; h += 8) {
            float4 e0 = *reinterpret_cast<const float4*>(eql + h);       // uniform b128 broadcast
            float4 e1 = *reinterpret_cast<const float4*>(eql + h + 4);
            float4 w0 = *reinterpret_cast<const float4*>(wv_lds + h);
            float4 w1 = *reinterpret_cast<const float4*>(wv_lds + h + 4);
            a0 = fmaf(w0.x, __builtin_amdgcn_rcpf(fmaf(e0.x, ek[h + 0], 1.f)), a0);
            a1 = fmaf(w0.y, __builtin_amdgcn_rcpf(fmaf(e0.y, ek[h + 1], 1.f)), a1);
            a2 = fmaf(w0.z, __builtin_amdgcn_rcpf(fmaf(e0.z, ek[h + 2], 1.f)), a2);
            a3 = fmaf(w0.w, __builtin_amdgcn_rcpf(fmaf(e0.w, ek[h + 3], 1.f)), a3);
            a0 = fmaf(w1.x, __builtin_amdgcn_rcpf(fmaf(e1.x, ek[h + 4], 1.f)), a0);
            a1 = fmaf(w1.y, __builtin_amdgcn_rcpf(fmaf(e1.y, ek[h + 5], 1.f)), a1);
            a2 = fmaf(w1.z, __builtin_amdgcn_rcpf(fmaf(e1.z, ek[h + 6], 1.f)), a2);
            a3 = fmaf(w1.w, __builtin_amdgcn_rcpf(fmaf(e1.w, ek[h + 7], 1.f)), a3);
        }
        float p = kvalid ? __builtin_amdgcn_exp2f(((a0 + a1) + (a2 + a3)) * NC2) : 0.f;
        p_lds[q][k] = p;                 // consecutive lanes: conflict-free b32
        float ps = p;
#pragma unroll
        for (int off = 32; off > 0; off >>= 1) ps += __shfl_xor(ps, off);
        if (l == 0) wsum[w][q] = ps;
    }

    // ---- PV: wave w consumes ONLY its own k-chunk's p (self-written -> no barrier).
    // lane = d column; each V row read exactly once per block (coalesced, L2-resident).
    const float* __restrict__ Vb = V + (size_t)b * 512 * 64;
    float acc[8] = {0.f, 0.f, 0.f, 0.f, 0.f, 0.f, 0.f, 0.f};
    const int kb = w * 64;
#pragma unroll 4
    for (int kk = 0; kk < 64; kk += 4) {
        const int k0 = kb + kk;
        float4 pq[8];
#pragma unroll
        for (int q = 0; q < 8; ++q)
            pq[q] = *reinterpret_cast<const float4*>(&p_lds[q][k0]);   // uniform broadcast b128
        float v0 = Vb[(size_t)(k0 + 0) * 64 + l];
        float v1 = Vb[(size_t)(k0 + 1) * 64 + l];
        float v2 = Vb[(size_t)(k0 + 2) * 64 + l];
        float v3 = Vb[(size_t)(k0 + 3) * 64 + l];
#pragma unroll
        for (int q = 0; q < 8; ++q) {
            acc[q] = fmaf(pq[q].x, v0, acc[q]);
            acc[q] = fmaf(pq[q].y, v1, acc[q]);
            acc[q] = fmaf(pq[q].z, v2, acc[q]);
            acc[q] = fmaf(pq[q].w, v3, acc[q]);
        }
    }
#pragma unroll
    for (int q = 0; q < 8; ++q)
        part_lds[(w * 8 + q) * 64 + l] = acc[q];
    __syncthreads();

    // ---- combine: wave w owns output q-row w, lane = d
    float denom = 0.f, o = 0.f;
#pragma unroll
    for (int ww = 0; ww < 8; ++ww) {
        denom += wsum[ww][w];                         // uniform broadcast
        o     += part_lds[(ww * 8 + w) * 64 + l];     // consecutive lanes
    }
    out[(size_t)(b * 512 + q0 + w) * 64 + l] = o * __builtin_amdgcn_rcpf(denom);
}

extern "C" void kernel_launch(void* const* d_in, const int* in_sizes, int n_in,
                              void* d_out, int out_size, void* d_ws, size_t ws_size,
                              hipStream_t stream) {
    (void)in_sizes; (void)n_in; (void)out_size; (void)ws_size;
    const float* queries = (const float*)d_in[0];
    const float* keys    = (const float*)d_in[1];
    const float* values  = (const float*)d_in[2];
    const int*   vlens   = (const int*)d_in[3];
    const float* Wq      = (const float*)d_in[4];
    const float* Wk      = (const float*)d_in[5];
    const float* wv      = (const float*)d_in[6];
    float* out = (float*)d_out;

    float* Eq = (float*)d_ws;                 // 8*512*64 floats = 1 MB
    float* Ek = Eq + 8 * 512 * 64;            // 1 MB

    proj_exp_kernel<<<2048, 256, 0, stream>>>(queries, keys, Wq, Wk, Eq, Ek);
    attn_kernel<<<512, 512, 0, stream>>>(Eq, Ek, wv, values, vlens, out);
}

// Round 9
// 39.017 us; speedup vs baseline: 1.1665x; 1.1665x over previous
//
#include <hip/hip_runtime.h>

#define C2   2.8853900817779268f    //  2*log2(e)
#define NC2 -2.8853900817779268f    // -2*log2(e)

// Kernel 1: projection + exp precompute. 512 blocks x 16 rows (4x less W-load
// traffic than the 2048x4 version: 8 MB instead of 33 MB through L2).
// Eq[b*512+q][h] = exp2(clamp(C2 * (queries @ Wq)[q][h], +-60)), Ek likewise (row-major).
__global__ __launch_bounds__(256) void proj_exp_kernel(
    const float* __restrict__ queries,
    const float* __restrict__ keys,
    const float* __restrict__ Wq,
    const float* __restrict__ Wk,
    float* __restrict__ Eq,
    float* __restrict__ Ek)
{
    __shared__ float w_lds[64 * 64];     // 16 KB
    __shared__ float in_lds[16 * 64];    // 4 KB

    const int t   = threadIdx.x;
    const int blk = blockIdx.x;          // 0..511
    const int r0  = blk * 16;            // virtual row among 8192
    const bool isQ = (r0 < 4096);
    const float* __restrict__ W  = isQ ? Wq : Wk;
    const float* __restrict__ in = isQ ? queries : keys;
    float* __restrict__ Eo       = isQ ? Eq : Ek;
    const int rbase = isQ ? r0 : (r0 - 4096);

#pragma unroll
    for (int i = 0; i < 16; ++i)
        w_lds[t + i * 256] = W[t + i * 256];
#pragma unroll
    for (int i = 0; i < 4; ++i)
        in_lds[t + i * 256] = in[(size_t)rbase * 64 + t + i * 256];
    __syncthreads();

    const int h  = t & 63;
    const int rg = t >> 6;               // row group 0..3 (rows rg*4 .. rg*4+3)
    const float* inr = &in_lds[rg * 4 * 64];
    float acc0 = 0.f, acc1 = 0.f, acc2 = 0.f, acc3 = 0.f;
#pragma unroll
    for (int i = 0; i < 64; i += 4) {
        float4 r0_ = *reinterpret_cast<const float4*>(inr + 0 * 64 + i);  // uniform b128
        float4 r1_ = *reinterpret_cast<const float4*>(inr + 1 * 64 + i);
        float4 r2_ = *reinterpret_cast<const float4*>(inr + 2 * 64 + i);
        float4 r3_ = *reinterpret_cast<const float4*>(inr + 3 * 64 + i);
        float w0 = w_lds[(i + 0) * 64 + h];
        float w1 = w_lds[(i + 1) * 64 + h];
        float w2 = w_lds[(i + 2) * 64 + h];
        float w3 = w_lds[(i + 3) * 64 + h];
        acc0 = fmaf(r0_.x, w0, acc0); acc0 = fmaf(r0_.y, w1, acc0);
        acc0 = fmaf(r0_.z, w2, acc0); acc0 = fmaf(r0_.w, w3, acc0);
        acc1 = fmaf(r1_.x, w0, acc1); acc1 = fmaf(r1_.y, w1, acc1);
        acc1 = fmaf(r1_.z, w2, acc1); acc1 = fmaf(r1_.w, w3, acc1);
        acc2 = fmaf(r2_.x, w0, acc2); acc2 = fmaf(r2_.y, w1, acc2);
        acc2 = fmaf(r2_.z, w2, acc2); acc2 = fmaf(r2_.w, w3, acc2);
        acc3 = fmaf(r3_.x, w0, acc3); acc3 = fmaf(r3_.y, w1, acc3);
        acc3 = fmaf(r3_.z, w2, acc3); acc3 = fmaf(r3_.w, w3, acc3);
    }
    float a[4] = {acc0, acc1, acc2, acc3};
#pragma unroll
    for (int j = 0; j < 4; ++j) {
        float x = fminf(fmaxf(a[j] * C2, -60.f), 60.f);  // bounded: products < 2^120
        Eo[(size_t)(rbase + rg * 4 + j) * 64 + h] = __builtin_amdgcn_exp2f(x);
    }
}

// Kernel 2: fused scores + softmax + PV, register-resident Ek (R5 structure).
// Block = 8 waves x 64 lanes; lane l of wave w owns k = w*64+l (Ek row in 64
// VGPRs) for 8 q-rows. Inner loop: ek in VGPRs, eq/wv wave-uniform -> scalar
// (SGPR) operands; zero LDS/VMEM per element.
// vs R5: (1) softmax reduce REMOVED from the q loop -- denominator is computed
// in the combine phase from p_lds (8 ds_read + 1 butterfly per wave, replacing
// 8 serial 6-shfl chains); (2) 4 accumulation chains for rcp-latency ILP.
// __launch_bounds__(512,4): 128-VGPR cap, 2 blocks/CU (grid 512) -- the proven
// no-spill sweet spot (R6/R8 showed both tighter and looser bounds regress).
// score'[q][k] = -2 * sum_h wv[h] * rcp(1 + Eq[q][h]*Ek[k][h])  (softmax-shift-invariant)
// p = exp2(score'*log2e), no max subtraction (|score'| <= 2*sum|wv| ~ 26, fp32-safe;
// masked k -> p = 0 exactly). Score and PV phases are wave-local: one barrier total.
__global__ __launch_bounds__(512, 4) void attn_kernel(
    const float* __restrict__ Eq,
    const float* __restrict__ Ek,
    const float* __restrict__ wv,
    const float* __restrict__ V,
    const int* __restrict__ valid_lens,
    float* __restrict__ out)
{
    __shared__ float p_lds[8][512];        // [q][k]
    __shared__ float part_lds[8 * 8 * 64]; // [w][q][d] PV partials

    const int t   = threadIdx.x;
    const int bid = blockIdx.x;          // 0..511
    const int b   = bid >> 6;
    const int q0  = (bid & 63) << 3;
    const int l   = t & 63;
    const int w   = __builtin_amdgcn_readfirstlane(threadIdx.x >> 6);  // uniform wave id
    const int vl  = valid_lens[b];
    const int k   = w * 64 + l;
    const bool kvalid = (k < vl);

    // ---- lane-resident Ek row: 64 VGPRs, loaded once (L2-resident)
    float ek[64];
    {
        const float4* ekr = reinterpret_cast<const float4*>(Ek + (size_t)(b * 512 + k) * 64);
#pragma unroll
        for (int i = 0; i < 16; ++i) {
            float4 v = ekr[i];
            ek[4 * i + 0] = v.x; ek[4 * i + 1] = v.y;
            ek[4 * i + 2] = v.z; ek[4 * i + 3] = v.w;
        }
    }

    const float* __restrict__ eqbase = Eq + (size_t)(b * 512 + q0) * 64;

    // ---- score phase: pure ALU (eq/wv scalar operands), no reductions
#pragma unroll 1
    for (int q = 0; q < 8; ++q) {
        const float* __restrict__ eqp = eqbase + q * 64;   // wave-uniform -> s_load
        float a0 = 0.f, a1 = 0.f, a2 = 0.f, a3 = 0.f;
#pragma unroll
        for (int h = 0; h < 64; h += 4) {
            a0 = fmaf(wv[h + 0], __builtin_amdgcn_rcpf(fmaf(eqp[h + 0], ek[h + 0], 1.f)), a0);
            a1 = fmaf(wv[h + 1], __builtin_amdgcn_rcpf(fmaf(eqp[h + 1], ek[h + 1], 1.f)), a1);
            a2 = fmaf(wv[h + 2], __builtin_amdgcn_rcpf(fmaf(eqp[h + 2], ek[h + 2], 1.f)), a2);
            a3 = fmaf(wv[h + 3], __builtin_amdgcn_rcpf(fmaf(eqp[h + 3], ek[h + 3], 1.f)), a3);
        }
        float p = kvalid ? __builtin_amdgcn_exp2f(((a0 + a1) + (a2 + a3)) * NC2) : 0.f;
        p_lds[q][k] = p;                 // consecutive lanes: conflict-free b32
    }

    // ---- PV: wave w consumes ONLY its own k-chunk's p (self-written -> no barrier).
    // lane = d column; each V row read exactly once per block (coalesced, L2-resident).
    const float* __restrict__ Vb = V + (size_t)b * 512 * 64;
    float acc[8] = {0.f, 0.f, 0.f, 0.f, 0.f, 0.f, 0.f, 0.f};
    const int kb = w * 64;
#pragma unroll 4
    for (int kk = 0; kk < 64; kk += 4) {
        const int k0 = kb + kk;
        float4 pq[8];
#pragma unroll
        for (int q = 0; q < 8; ++q)
            pq[q] = *reinterpret_cast<const float4*>(&p_lds[q][k0]);   // uniform broadcast b128
        float v0 = Vb[(size_t)(k0 + 0) * 64 + l];
        float v1 = Vb[(size_t)(k0 + 1) * 64 + l];
        float v2 = Vb[(size_t)(k0 + 2) * 64 + l];
        float v3 = Vb[(size_t)(k0 + 3) * 64 + l];
#pragma unroll
        for (int q = 0; q < 8; ++q) {
            acc[q] = fmaf(pq[q].x, v0, acc[q]);
            acc[q] = fmaf(pq[q].y, v1, acc[q]);
            acc[q] = fmaf(pq[q].z, v2, acc[q]);
            acc[q] = fmaf(pq[q].w, v3, acc[q]);
        }
    }
#pragma unroll
    for (int q = 0; q < 8; ++q)
        part_lds[(w * 8 + q) * 64 + l] = acc[q];
    __syncthreads();                     // the kernel's only barrier

    // ---- combine: wave w owns output q-row w, lane = d.
    // Softmax denominator computed HERE from p_lds (one reduce per wave total).
    float dsum = 0.f;
#pragma unroll
    for (int j = 0; j < 8; ++j)
        dsum += p_lds[w][j * 64 + l];                 // conflict-free b32
#pragma unroll
    for (int off = 32; off > 0; off >>= 1)
        dsum += __shfl_xor(dsum, off);                // butterfly: all lanes get total

    float o = 0.f;
#pragma unroll
    for (int ww = 0; ww < 8; ++ww)
        o += part_lds[(ww * 8 + w) * 64 + l];         // consecutive lanes
    out[(size_t)(b * 512 + q0 + w) * 64 + l] = o * __builtin_amdgcn_rcpf(dsum);
}

extern "C" void kernel_launch(void* const* d_in, const int* in_sizes, int n_in,
                              void* d_out, int out_size, void* d_ws, size_t ws_size,
                              hipStream_t stream) {
    (void)in_sizes; (void)n_in; (void)out_size; (void)ws_size;
    const float* queries = (const float*)d_in[0];
    const float* keys    = (const float*)d_in[1];
    const float* values  = (const float*)d_in[2];
    const int*   vlens   = (const int*)d_in[3];
    const float* Wq      = (const float*)d_in[4];
    const float* Wk      = (const float*)d_in[5];
    const float* wv      = (const float*)d_in[6];
    float* out = (float*)d_out;

    float* Eq = (float*)d_ws;                 // 8*512*64 floats = 1 MB
    float* Ek = Eq + 8 * 512 * 64;            // 1 MB

    proj_exp_kernel<<<512, 256, 0, stream>>>(queries, keys, Wq, Wk, Eq, Ek);
    attn_kernel<<<512, 512, 0, stream>>>(Eq, Ek, wv, values, vlens, out);
}